// Round 1
// baseline (856.781 us; speedup 1.0000x reference)
//
#include <hip/hip_runtime.h>
#include <math.h>

#define NA 131072
#define NBLK (NA/64)

// ws layout (floats)
#define OFF_WG4   0            // [150][160][4]  (r,z,n,0) transposed W_hh
#define OFF_WI4   96000        // [12][160][4]   (r,z,n,0) transposed W_ih
#define OFF_B4    103680       // [160][4]       (bR, bZ, bXN, bHN)
#define OFF_WT1   104320       // [200][64]      W1^T zero-padded
#define OFF_WT2   117120       // [50][64]       W2^T zero-padded
#define OFF_WT3   120320       // [50][8]        W3^T zero-padded

__global__ __launch_bounds__(256) void prep_kernel(
    const float* __restrict__ W_ih, const float* __restrict__ W_hh,
    const float* __restrict__ b_ih, const float* __restrict__ b_hh,
    const float* __restrict__ W1, const float* __restrict__ W2, const float* __restrict__ W3,
    float* __restrict__ ws)
{
  int tid = blockIdx.x*blockDim.x + threadIdx.x;
  int stride = gridDim.x*blockDim.x;
  float* WG4 = ws + OFF_WG4;
  float* WI4 = ws + OFF_WI4;
  float* B4  = ws + OFF_B4;
  float* WT1 = ws + OFF_WT1;
  float* WT2 = ws + OFF_WT2;
  float* WT3 = ws + OFF_WT3;
  for (int idx = tid; idx < 150*160; idx += stride) {
    int k = idx/160, j = idx - k*160;
    float r=0.f,z=0.f,n=0.f;
    if (j<150) { r = W_hh[j*150+k]; z = W_hh[(150+j)*150+k]; n = W_hh[(300+j)*150+k]; }
    WG4[idx*4+0]=r; WG4[idx*4+1]=z; WG4[idx*4+2]=n; WG4[idx*4+3]=0.f;
  }
  for (int idx = tid; idx < 12*160; idx += stride) {
    int k = idx/160, j = idx - k*160;
    float r=0.f,z=0.f,n=0.f;
    if (j<150) { r = W_ih[j*12+k]; z = W_ih[(150+j)*12+k]; n = W_ih[(300+j)*12+k]; }
    WI4[idx*4+0]=r; WI4[idx*4+1]=z; WI4[idx*4+2]=n; WI4[idx*4+3]=0.f;
  }
  for (int j = tid; j < 160; j += stride) {
    float br=0.f,bz=0.f,bxn=0.f,bhn=0.f;
    if (j<150){ br=b_ih[j]+b_hh[j]; bz=b_ih[150+j]+b_hh[150+j]; bxn=b_ih[300+j]; bhn=b_hh[300+j]; }
    B4[j*4+0]=br; B4[j*4+1]=bz; B4[j*4+2]=bxn; B4[j*4+3]=bhn;
  }
  for (int idx = tid; idx < 200*64; idx += stride) {
    int k = idx/64, o = idx - k*64;
    WT1[idx] = (o<50) ? W1[o*200+k] : 0.f;
  }
  for (int idx = tid; idx < 50*64; idx += stride) {
    int k = idx/64, o = idx - k*64;
    WT2[idx] = (o<50) ? W2[o*50+k] : 0.f;
  }
  for (int idx = tid; idx < 50*8; idx += stride) {
    int k = idx/8, o = idx - k*8;
    WT3[idx] = (o<6) ? W3[o*50+k] : 0.f;
  }
}

__global__ __launch_bounds__(256) void gru_kernel(
    const float* __restrict__ x_flat, const float* __restrict__ h_in,
    const float* __restrict__ ws, float* __restrict__ out)
{
  __shared__ float sh_h[150*72];   // k-major: sh_h[k*72 + a], 16B-aligned rows
  __shared__ float sh_x[64*13];
  const float* WG4 = ws + OFF_WG4;
  const float* WI4 = ws + OFF_WI4;
  const float* B4  = ws + OFF_B4;
  int t = threadIdx.x;
  long ab = (long)blockIdx.x * 64;
  for (int idx = t; idx < 64*150; idx += 256) {
    int a = idx/150, k = idx - a*150;
    sh_h[k*72 + a] = h_in[(ab+a)*150 + k];
  }
  for (int idx = t; idx < 64*12; idx += 256) {
    int a = idx/12, k = idx - a*12;
    sh_x[a*13 + k] = x_flat[(ab+a)*12 + k];
  }
  __syncthreads();
  int tg = t & 15;        // j sub-slot
  int ta = t >> 4;        // agent group (4 agents each)
  float* outh = out + (size_t)8*NA;
  #pragma unroll 1
  for (int j0 = 0; j0 < 160; j0 += 32) {
    int jA = j0 + tg, jB = j0 + tg + 16;
    float accR[2][4], accZ[2][4], accXN[2][4], accHN[2][4];
    #pragma unroll
    for (int m=0;m<2;m++){
      int j = m ? jB : jA;
      float4 b = *reinterpret_cast<const float4*>(&B4[j*4]);
      #pragma unroll
      for (int i=0;i<4;i++){ accR[m][i]=b.x; accZ[m][i]=b.y; accXN[m][i]=b.z; accHN[m][i]=b.w; }
    }
    // K = 150 recurrent GEMM
    #pragma unroll 2
    for (int k=0;k<150;k++){
      float4 hv = *reinterpret_cast<const float4*>(&sh_h[k*72 + ta*4]);
      float hvv[4] = {hv.x, hv.y, hv.z, hv.w};
      #pragma unroll
      for (int m=0;m<2;m++){
        int j = m ? jB : jA;
        float4 w = *reinterpret_cast<const float4*>(&WG4[(k*160 + j)*4]);
        #pragma unroll
        for (int i=0;i<4;i++){
          accR[m][i]  = fmaf(hvv[i], w.x, accR[m][i]);
          accZ[m][i]  = fmaf(hvv[i], w.y, accZ[m][i]);
          accHN[m][i] = fmaf(hvv[i], w.z, accHN[m][i]);
        }
      }
    }
    // K = 12 input GEMM
    #pragma unroll
    for (int k=0;k<12;k++){
      float xv[4];
      #pragma unroll
      for (int i=0;i<4;i++) xv[i] = sh_x[(ta*4+i)*13 + k];
      #pragma unroll
      for (int m=0;m<2;m++){
        int j = m ? jB : jA;
        float4 w = *reinterpret_cast<const float4*>(&WI4[(k*160 + j)*4]);
        #pragma unroll
        for (int i=0;i<4;i++){
          accR[m][i]  = fmaf(xv[i], w.x, accR[m][i]);
          accZ[m][i]  = fmaf(xv[i], w.y, accZ[m][i]);
          accXN[m][i] = fmaf(xv[i], w.z, accXN[m][i]);
        }
      }
    }
    // gate math + h_new
    #pragma unroll
    for (int m=0;m<2;m++){
      int j = m ? jB : jA;
      if (j < 150) {
        #pragma unroll
        for (int i=0;i<4;i++){
          int a = ta*4+i;
          float h0 = sh_h[j*72 + a];
          float r = 1.f/(1.f+expf(-accR[m][i]));
          float z = 1.f/(1.f+expf(-accZ[m][i]));
          float n = tanhf(accXN[m][i] + r*accHN[m][i]);
          outh[(ab+a)*150 + j] = (1.f - z)*n + z*h0;
        }
      }
    }
  }
}

__global__ __launch_bounds__(256) void mlp_kernel(
    const float* __restrict__ z_in, const float* __restrict__ st,
    const float* __restrict__ dx, const float* __restrict__ xp,
    const float* __restrict__ b1, const float* __restrict__ b2, const float* __restrict__ b3,
    const float* __restrict__ ws, float* __restrict__ out)
{
  __shared__ float sh_d[64*201];   // [h_new(150), static(50)] per agent
  __shared__ float sh_v1[64*53];
  const float* WT1 = ws + OFF_WT1;
  const float* WT2 = ws + OFF_WT2;
  const float* WT3 = ws + OFF_WT3;
  int t = threadIdx.x;
  long ab = (long)blockIdx.x*64;
  const float* outh = out + (size_t)8*NA;
  for (int idx = t; idx < 64*200; idx += 256){
    int a = idx/200, c = idx - a*200;
    float v = (c<150) ? outh[(ab+a)*150+c] : st[(ab+a)*50 + (c-150)];
    sh_d[a*201+c] = v;
  }
  __syncthreads();
  int a = t & 63, half = t >> 6;   // wave-uniform half
  int ob = half*16;
  // MLP1: 200 -> 50 (padded 64), softplus
  float acc[16];
  #pragma unroll
  for (int q=0;q<16;q++){ int o=ob+q; acc[q] = (o<50)? b1[o] : 0.f; }
  for (int k=0;k<200;k++){
    float dv = sh_d[a*201+k];
    const float4* wp = reinterpret_cast<const float4*>(&WT1[k*64+ob]);
    #pragma unroll
    for (int q4=0;q4<4;q4++){
      float4 w = wp[q4];
      acc[q4*4+0] = fmaf(dv, w.x, acc[q4*4+0]);
      acc[q4*4+1] = fmaf(dv, w.y, acc[q4*4+1]);
      acc[q4*4+2] = fmaf(dv, w.z, acc[q4*4+2]);
      acc[q4*4+3] = fmaf(dv, w.w, acc[q4*4+3]);
    }
  }
  #pragma unroll
  for (int q=0;q<16;q++){
    int o = ob+q;
    if (o<50){
      float xx = acc[q];
      sh_v1[a*53+o] = fmaxf(xx,0.f) + log1pf(expf(-fabsf(xx)));
    }
  }
  __syncthreads();
  // MLP2: 50 -> 50, tanh
  float acc2[16];
  #pragma unroll
  for (int q=0;q<16;q++){ int o=ob+q; acc2[q] = (o<50)? b2[o] : 0.f; }
  for (int k=0;k<50;k++){
    float dv = sh_v1[a*53+k];
    const float4* wp = reinterpret_cast<const float4*>(&WT2[k*64+ob]);
    #pragma unroll
    for (int q4=0;q4<4;q4++){
      float4 w = wp[q4];
      acc2[q4*4+0] = fmaf(dv, w.x, acc2[q4*4+0]);
      acc2[q4*4+1] = fmaf(dv, w.y, acc2[q4*4+1]);
      acc2[q4*4+2] = fmaf(dv, w.z, acc2[q4*4+2]);
      acc2[q4*4+3] = fmaf(dv, w.w, acc2[q4*4+3]);
    }
  }
  float* sh_v2 = sh_d;   // reuse (all sh_d reads completed before previous sync)
  #pragma unroll
  for (int q=0;q<16;q++){
    int o = ob+q;
    if (o<50) sh_v2[a*53+o] = tanhf(acc2[q]);
  }
  __syncthreads();
  // head: 50 -> 6 + distribution math (one thread per agent)
  if (half==0){
    float o6[6];
    #pragma unroll
    for (int jj=0;jj<6;jj++) o6[jj]=b3[jj];
    for (int k=0;k<50;k++){
      float v = sh_v2[a*53+k];
      #pragma unroll
      for (int jj=0;jj<6;jj++) o6[jj] = fmaf(v, WT3[k*8+jj], o6[jj]);
    }
    long ga = ab + a;
    float mu0 = xp[ga*2+0] + 0.5f*dx[ga*2+0] + o6[0];
    float mu1 = xp[ga*2+1] + 0.5f*dx[ga*2+1] + o6[1];
    float bb  = o6[3] + o6[4];
    float apd = o6[2] + o6[5];
    float amd = o6[2] - o6[5];
    float delta = sqrtf(amd*amd + bb*bb);
    float e  = expf(delta);
    float ei = 1.f/e;
    float sinh_ = 0.5f*(e - ei);
    float cosh_ = 0.5f*(e + ei);
    float tmp1 = sinh_/delta;
    float tmp2 = amd/tmp1;
    float ea = expf(apd);
    float s00 = (cosh_+tmp2)*ea;
    float s01 = (bb*tmp1)*ea;
    float s11 = (cosh_-tmp2)*ea;
    float z0 = z_in[ga*2+0], z1 = z_in[ga*2+1];
    out[ga*2+0] = s00*z0 + s01*z1 + mu0;
    out[ga*2+1] = s01*z0 + s11*z1 + mu1;
    out[(size_t)2*NA + ga*2+0] = mu0;
    out[(size_t)2*NA + ga*2+1] = mu1;
    out[(size_t)4*NA + ga*4+0] = s00;
    out[(size_t)4*NA + ga*4+1] = s01;
    out[(size_t)4*NA + ga*4+2] = s01;
    out[(size_t)4*NA + ga*4+3] = s11;
  }
}

extern "C" void kernel_launch(void* const* d_in, const int* in_sizes, int n_in,
                              void* d_out, int out_size, void* d_ws, size_t ws_size,
                              hipStream_t stream) {
  const float* z      = (const float*)d_in[0];
  const float* x_flat = (const float*)d_in[1];
  const float* h      = (const float*)d_in[2];
  const float* st     = (const float*)d_in[3];
  const float* dx     = (const float*)d_in[4];
  const float* xp     = (const float*)d_in[5];
  const float* W_ih   = (const float*)d_in[6];
  const float* W_hh   = (const float*)d_in[7];
  const float* b_ih   = (const float*)d_in[8];
  const float* b_hh   = (const float*)d_in[9];
  const float* W1     = (const float*)d_in[10];
  const float* b1     = (const float*)d_in[11];
  const float* W2     = (const float*)d_in[12];
  const float* b2     = (const float*)d_in[13];
  const float* W3     = (const float*)d_in[14];
  const float* b3     = (const float*)d_in[15];
  float* out = (float*)d_out;
  float* ws  = (float*)d_ws;

  hipLaunchKernelGGL(prep_kernel, dim3(128), dim3(256), 0, stream,
                     W_ih, W_hh, b_ih, b_hh, W1, W2, W3, ws);
  hipLaunchKernelGGL(gru_kernel, dim3(NBLK), dim3(256), 0, stream,
                     x_flat, h, ws, out);
  hipLaunchKernelGGL(mlp_kernel, dim3(NBLK), dim3(256), 0, stream,
                     z, st, dx, xp, b1, b2, b3, ws, out);
}

// Round 2
// 192.963 us; speedup vs baseline: 4.4401x; 4.4401x over previous
//
#include <hip/hip_runtime.h>
#include <math.h>

#define NA 131072
#define NBLK (NA/64)

typedef __bf16 bf16x8 __attribute__((ext_vector_type(8)));
typedef float f32x16 __attribute__((ext_vector_type(16)));

// ws byte offsets
#define APACK_OFF 0           // 19*12*64*16 = 233472 B  (GRU weight frags)
#define BIAS4_OFF 233472      // 152*16      = 2432 B    (r,z,hn,xn biases)
#define W1P_OFF   235904      // 2*13*64*16  = 26624 B
#define W2P_OFF   262528      // 2*4*64*16   = 8192 B    -> end 270720

__device__ __forceinline__ unsigned short f2b(float f){
  __bf16 h = (__bf16)f;
  unsigned short u;
  __builtin_memcpy(&u, &h, 2);
  return u;
}
__device__ __forceinline__ bf16x8 asb(uint4 u){ return __builtin_bit_cast(bf16x8, u); }
__device__ __forceinline__ f32x16 mfma32(bf16x8 a, bf16x8 b, f32x16 c){
  return __builtin_amdgcn_mfma_f32_32x32x16_bf16(a, b, c, 0, 0, 0);
}
__device__ __forceinline__ uint4 packv(const unsigned short* v){
  uint4 p;
  p.x = (unsigned)v[0] | ((unsigned)v[1]<<16);
  p.y = (unsigned)v[2] | ((unsigned)v[3]<<16);
  p.z = (unsigned)v[4] | ((unsigned)v[5]<<16);
  p.w = (unsigned)v[6] | ((unsigned)v[7]<<16);
  return p;
}
__device__ __forceinline__ float fsigmoid(float x){ return 1.f/(1.f+__expf(-x)); }
__device__ __forceinline__ float ftanh(float x){ return 1.f - 2.f/(__expf(2.f*x)+1.f); }

// ---------------- prep: pack weights fragment-linear --------------------
// GRU combined weight W[R=4j+g][k], R<608 (j<152), k<192: k<150 = h-part,
// 150..161 = x-part. g: 0=r 1=z 2=hn 3=xn.
// Fragment layout (mfma_f32_32x32x16_bf16 A-operand): lane l holds
// A[mt*32 + (l&31)][ks*16 + (l>>5)*8 + i], i=0..7.
__global__ __launch_bounds__(256) void prep2(
    const float* __restrict__ W_ih, const float* __restrict__ W_hh,
    const float* __restrict__ b_ih, const float* __restrict__ b_hh,
    const float* __restrict__ W1, const float* __restrict__ W2,
    float* __restrict__ ws)
{
  int tid = blockIdx.x*blockDim.x + threadIdx.x;
  int stride = gridDim.x*blockDim.x;
  unsigned short* Ap  = (unsigned short*)((char*)ws + APACK_OFF);
  float*          B4  = (float*)((char*)ws + BIAS4_OFF);
  unsigned short* W1p = (unsigned short*)((char*)ws + W1P_OFF);
  unsigned short* W2p = (unsigned short*)((char*)ws + W2P_OFF);

  for (int s = tid; s < 19*12*64; s += stride){
    int lane = s & 63; int t2 = s >> 6; int ks = t2 % 12; int mt = t2 / 12;
    int R = mt*32 + (lane & 31);
    int kb = ks*16 + (lane >> 5)*8;
    int j = R >> 2, g = R & 3;
    #pragma unroll
    for (int i=0;i<8;i++){
      int k = kb + i; float f = 0.f;
      if (j < 150){
        if (k < 150){
          if (g==0) f = W_hh[j*150+k];
          else if (g==1) f = W_hh[(150+j)*150+k];
          else if (g==2) f = W_hh[(300+j)*150+k];
        } else if (k < 162){
          int kx = k - 150;
          if (g==0) f = W_ih[j*12+kx];
          else if (g==1) f = W_ih[(150+j)*12+kx];
          else if (g==3) f = W_ih[(300+j)*12+kx];
        }
      }
      Ap[s*8+i] = f2b(f);
    }
  }
  for (int j = tid; j < 152; j += stride){
    float4 bv = make_float4(0.f,0.f,0.f,0.f);
    if (j < 150){
      bv.x = b_ih[j]       + b_hh[j];
      bv.y = b_ih[150+j]   + b_hh[150+j];
      bv.z = b_hh[300+j];
      bv.w = b_ih[300+j];
    }
    ((float4*)B4)[j] = bv;
  }
  for (int s = tid; s < 2*13*64; s += stride){
    int lane = s & 63; int t2 = s >> 6; int ks = t2 % 13; int mt = t2 / 13;
    int o = mt*32 + (lane & 31);
    int kb = ks*16 + (lane >> 5)*8;
    #pragma unroll
    for (int i=0;i<8;i++){
      int k = kb + i;
      float f = (o < 50 && k < 200) ? W1[o*200+k] : 0.f;
      W1p[s*8+i] = f2b(f);
    }
  }
  for (int s = tid; s < 2*4*64; s += stride){
    int lane = s & 63; int t2 = s >> 6; int ks = t2 % 4; int mt = t2 / 4;
    int o = mt*32 + (lane & 31);
    int kb = ks*16 + (lane >> 5)*8;
    #pragma unroll
    for (int i=0;i<8;i++){
      int k = kb + i;
      float f = (o < 50 && k < 50) ? W2[o*50+k] : 0.f;
      W2p[s*8+i] = f2b(f);
    }
  }
}

// ---------------- GRU via MFMA -----------------------------------------
// M = 608 gate-rows (19 mtiles), N = 64 agents/block (2 ntiles), K = 192.
union GruSM {
  unsigned short bp[2*12*64*8];  // agent-data frags, 24576 B
  float hn[64*153];              // h_new collect,    39168 B
};

__global__ __launch_bounds__(256) void gru_mfma(
    const float* __restrict__ x_flat, const float* __restrict__ h_in,
    const unsigned short* __restrict__ Apack, const float* __restrict__ Bias4,
    float* __restrict__ out)
{
  __shared__ GruSM sm;
  int t = threadIdx.x; int lane = t & 63; int w = t >> 6;
  int hi = lane >> 5, cl = lane & 31;
  long ab = (long)blockIdx.x * 64;

  // stage agent-data fragments: B[k][agent], lane l holds
  // B[ks*16+(l>>5)*8+i][nt*32+(l&31)]
  for (int s = t; s < 2*12*64; s += 256){
    int ln = s & 63; int t2 = s >> 6; int ks = t2 % 12; int nt = t2 / 12;
    int agent = nt*32 + (ln & 31);
    int kb = ks*16 + (ln >> 5)*8;
    const float* hrow = h_in  + (ab + agent)*150;
    const float* xrow = x_flat + (ab + agent)*12;
    unsigned short v[8];
    #pragma unroll
    for (int i=0;i<8;i++){
      int k = kb + i; float f = 0.f;
      if (k < 150) f = hrow[k];
      else if (k < 162) f = xrow[k-150];
      v[i] = f2b(f);
    }
    *reinterpret_cast<uint4*>(&sm.bp[s*8]) = packv(v);
  }
  __syncthreads();

  // cache both ntiles' B-frags in registers (96 VGPR)
  bf16x8 B0[12], B1[12];
  #pragma unroll
  for (int ks=0;ks<12;ks++){
    B0[ks] = asb(*reinterpret_cast<const uint4*>(&sm.bp[((0*12+ks)*64+lane)*8]));
    B1[ks] = asb(*reinterpret_cast<const uint4*>(&sm.bp[((1*12+ks)*64+lane)*8]));
  }
  __syncthreads();   // LDS now reused for h_new

  const uint4* ApV = (const uint4*)Apack;
  for (int mt = w; mt < 19; mt += 4){
    f32x16 acc0;
    #pragma unroll
    for (int q=0;q<4;q++){
      int j = mt*8 + 2*q + hi;
      float4 bq = *reinterpret_cast<const float4*>(&Bias4[j*4]);
      acc0[4*q+0]=bq.x; acc0[4*q+1]=bq.y; acc0[4*q+2]=bq.z; acc0[4*q+3]=bq.w;
    }
    f32x16 acc1 = acc0;
    const uint4* ap = ApV + (size_t)(mt*12)*64 + lane;
    #pragma unroll
    for (int ks=0;ks<12;ks++){
      bf16x8 af = asb(ap[ks*64]);
      acc0 = mfma32(af, B0[ks], acc0);
      acc1 = mfma32(af, B1[ks], acc1);
    }
    // epilogue: lane holds 4 gate-rows (r,z,hn,xn) x 4 j-groups per ntile
    #pragma unroll
    for (int nt=0;nt<2;nt++){
      const f32x16& acc = nt ? acc1 : acc0;
      int agent = nt*32 + cl;
      const float* h0row = h_in + (ab + agent)*150;
      float* dsth = sm.hn + agent*153;
      #pragma unroll
      for (int q=0;q<4;q++){
        int j = mt*8 + 2*q + hi;
        if (j < 150){
          float pr  = acc[4*q+0];
          float pz  = acc[4*q+1];
          float phn = acc[4*q+2];
          float pxn = acc[4*q+3];
          float r = fsigmoid(pr);
          float z = fsigmoid(pz);
          float n = ftanh(pxn + r*phn);
          float h0 = h0row[j];
          dsth[j] = z*(h0 - n) + n;
        }
      }
    }
  }
  __syncthreads();
  // coalesced flush of h_new
  float* oh = out + (size_t)8*NA;
  for (int s = t; s < 64*150; s += 256){
    int a = s/150, j = s - a*150;
    oh[(ab+a)*150 + j] = sm.hn[a*153 + j];
  }
}

// ---------------- MLP + head via MFMA ----------------------------------
struct MlpSM {
  unsigned short dp[2*13*64*8];  // [h_new|static] frags, 26624 B
  unsigned short h1[64*72];      // softplus out (bf16),   9216 B
  float h2[64*53];               // tanh out (f32),       13568 B
};

__global__ __launch_bounds__(256) void mlp_mfma(
    const float* __restrict__ st, const float* __restrict__ z_in,
    const float* __restrict__ dx, const float* __restrict__ xp,
    const float* __restrict__ b1, const float* __restrict__ b2,
    const float* __restrict__ W3, const float* __restrict__ b3,
    const unsigned short* __restrict__ W1p, const unsigned short* __restrict__ W2p,
    float* __restrict__ out)
{
  __shared__ MlpSM sm;
  int t = threadIdx.x; int lane = t & 63; int w = t >> 6;
  int hi = lane >> 5, cl = lane & 31;
  long ab = (long)blockIdx.x * 64;
  const float* oh = out + (size_t)8*NA;

  for (int s = t; s < 64*72; s += 256) sm.h1[s] = 0;
  for (int s = t; s < 2*13*64; s += 256){
    int ln = s & 63; int t2 = s >> 6; int ks = t2 % 13; int nt = t2 / 13;
    int agent = nt*32 + (ln & 31);
    int kb = ks*16 + (ln >> 5)*8;
    const float* hrow = oh + (ab + agent)*150;
    const float* srow = st + (ab + agent)*50;
    unsigned short v[8];
    #pragma unroll
    for (int i=0;i<8;i++){
      int k = kb + i; float f = 0.f;
      if (k < 150) f = hrow[k];
      else if (k < 200) f = srow[k-150];
      v[i] = f2b(f);
    }
    *reinterpret_cast<uint4*>(&sm.dp[s*8]) = packv(v);
  }
  __syncthreads();

  int mt = w >> 1, nt = w & 1;
  // ---- MLP1: 200 -> 50, softplus ----
  f32x16 acc;
  #pragma unroll
  for (int r=0;r<16;r++){
    int o = mt*32 + (r&3) + 8*(r>>2) + 4*hi;
    acc[r] = (o < 50) ? b1[o] : 0.f;
  }
  #pragma unroll
  for (int ks=0;ks<13;ks++){
    bf16x8 bf = asb(*reinterpret_cast<const uint4*>(&sm.dp[((nt*13+ks)*64+lane)*8]));
    bf16x8 af = asb(((const uint4*)W1p)[(mt*13+ks)*64+lane]);
    acc = mfma32(af, bf, acc);
  }
  #pragma unroll
  for (int r=0;r<16;r++){
    int o = mt*32 + (r&3) + 8*(r>>2) + 4*hi;
    if (o < 50){
      float xx = acc[r];
      float spv = fmaxf(xx,0.f) + __logf(1.f + __expf(-fabsf(xx)));
      sm.h1[(nt*32+cl)*72 + o] = f2b(spv);
    }
  }
  __syncthreads();

  // ---- MLP2: 50 -> 50, tanh ----
  f32x16 acc2;
  #pragma unroll
  for (int r=0;r<16;r++){
    int o = mt*32 + (r&3) + 8*(r>>2) + 4*hi;
    acc2[r] = (o < 50) ? b2[o] : 0.f;
  }
  #pragma unroll
  for (int ks=0;ks<4;ks++){
    bf16x8 bf = asb(*reinterpret_cast<const uint4*>(&sm.h1[(nt*32+cl)*72 + ks*16 + hi*8]));
    bf16x8 af = asb(((const uint4*)W2p)[(mt*4+ks)*64+lane]);
    acc2 = mfma32(af, bf, acc2);
  }
  #pragma unroll
  for (int r=0;r<16;r++){
    int o = mt*32 + (r&3) + 8*(r>>2) + 4*hi;
    if (o < 50) sm.h2[(nt*32+cl)*53 + o] = ftanh(acc2[r]);
  }
  __syncthreads();

  // ---- head: 50 -> 6 + distribution math (one thread per agent) ----
  if (t < 64){
    int a = t; long ga = ab + a;
    float o6[6];
    #pragma unroll
    for (int jj=0;jj<6;jj++) o6[jj] = b3[jj];
    for (int k=0;k<50;k++){
      float v = sm.h2[a*53+k];
      #pragma unroll
      for (int jj=0;jj<6;jj++) o6[jj] = fmaf(v, W3[jj*50+k], o6[jj]);
    }
    float mu0 = xp[ga*2+0] + 0.5f*dx[ga*2+0] + o6[0];
    float mu1 = xp[ga*2+1] + 0.5f*dx[ga*2+1] + o6[1];
    float bb  = o6[3] + o6[4];
    float apd = o6[2] + o6[5];
    float amd = o6[2] - o6[5];
    float delta = sqrtf(amd*amd + bb*bb);
    float e  = __expf(delta * 1.0f);
    float ei = 1.f/e;
    float sinh_ = 0.5f*(e - ei);
    float cosh_ = 0.5f*(e + ei);
    float tmp1 = sinh_/delta;
    float tmp2 = amd/tmp1;
    float ea = __expf(apd);
    float s00 = (cosh_+tmp2)*ea;
    float s01 = (bb*tmp1)*ea;
    float s11 = (cosh_-tmp2)*ea;
    float z0 = z_in[ga*2+0], z1 = z_in[ga*2+1];
    out[ga*2+0] = s00*z0 + s01*z1 + mu0;
    out[ga*2+1] = s01*z0 + s11*z1 + mu1;
    out[(size_t)2*NA + ga*2+0] = mu0;
    out[(size_t)2*NA + ga*2+1] = mu1;
    out[(size_t)4*NA + ga*4+0] = s00;
    out[(size_t)4*NA + ga*4+1] = s01;
    out[(size_t)4*NA + ga*4+2] = s01;
    out[(size_t)4*NA + ga*4+3] = s11;
  }
}

extern "C" void kernel_launch(void* const* d_in, const int* in_sizes, int n_in,
                              void* d_out, int out_size, void* d_ws, size_t ws_size,
                              hipStream_t stream) {
  const float* z      = (const float*)d_in[0];
  const float* x_flat = (const float*)d_in[1];
  const float* h      = (const float*)d_in[2];
  const float* st     = (const float*)d_in[3];
  const float* dx     = (const float*)d_in[4];
  const float* xp     = (const float*)d_in[5];
  const float* W_ih   = (const float*)d_in[6];
  const float* W_hh   = (const float*)d_in[7];
  const float* b_ih   = (const float*)d_in[8];
  const float* b_hh   = (const float*)d_in[9];
  const float* W1     = (const float*)d_in[10];
  const float* b1     = (const float*)d_in[11];
  const float* W2     = (const float*)d_in[12];
  const float* b2     = (const float*)d_in[13];
  const float* W3     = (const float*)d_in[14];
  const float* b3     = (const float*)d_in[15];
  float* out = (float*)d_out;
  float* ws  = (float*)d_ws;

  const unsigned short* Apack = (const unsigned short*)((char*)ws + APACK_OFF);
  const float*          Bias4 = (const float*)((char*)ws + BIAS4_OFF);
  const unsigned short* W1p   = (const unsigned short*)((char*)ws + W1P_OFF);
  const unsigned short* W2p   = (const unsigned short*)((char*)ws + W2P_OFF);

  hipLaunchKernelGGL(prep2, dim3(128), dim3(256), 0, stream,
                     W_ih, W_hh, b_ih, b_hh, W1, W2, ws);
  hipLaunchKernelGGL(gru_mfma, dim3(NBLK), dim3(256), 0, stream,
                     x_flat, h, Apack, Bias4, out);
  hipLaunchKernelGGL(mlp_mfma, dim3(NBLK), dim3(256), 0, stream,
                     st, z, dx, xp, b1, b2, W3, b3, W1p, W2p, out);
}

// Round 3
// 115.110 us; speedup vs baseline: 7.4431x; 1.6763x over previous
//
#include <hip/hip_runtime.h>
#include <math.h>

#define NA 131072
#define NBLK (NA/64)

typedef __bf16 bf16x8 __attribute__((ext_vector_type(8)));
typedef float f32x16 __attribute__((ext_vector_type(16)));

// ws byte offsets
#define APACK_OFF 0           // 19*12*64*16 = 233472 B  (GRU weight frags)
#define BIAS4_OFF 233472      // 152*16      = 2432 B    (r,z,hn,xn biases)
#define W1P_OFF   235904      // 2*13*64*16  = 26624 B
#define W2P_OFF   262528      // 2*4*64*16   = 8192 B    -> end 270720

__device__ __forceinline__ unsigned short f2b(float f){
  __bf16 h = (__bf16)f;
  unsigned short u;
  __builtin_memcpy(&u, &h, 2);
  return u;
}
__device__ __forceinline__ float b2f(unsigned short u){
  unsigned x = ((unsigned)u) << 16; float f;
  __builtin_memcpy(&f, &x, 4); return f;
}
__device__ __forceinline__ bf16x8 asb(uint4 u){ return __builtin_bit_cast(bf16x8, u); }
__device__ __forceinline__ f32x16 mfma32(bf16x8 a, bf16x8 b, f32x16 c){
  return __builtin_amdgcn_mfma_f32_32x32x16_bf16(a, b, c, 0, 0, 0);
}
__device__ __forceinline__ uint4 packv(const unsigned short* v){
  uint4 p;
  p.x = (unsigned)v[0] | ((unsigned)v[1]<<16);
  p.y = (unsigned)v[2] | ((unsigned)v[3]<<16);
  p.z = (unsigned)v[4] | ((unsigned)v[5]<<16);
  p.w = (unsigned)v[6] | ((unsigned)v[7]<<16);
  return p;
}
__device__ __forceinline__ float fsigmoid(float x){ return 1.f/(1.f+__expf(-x)); }
__device__ __forceinline__ float ftanh(float x){ return 1.f - 2.f/(__expf(2.f*x)+1.f); }

// ---------------- prep: pack weights fragment-linear (as round 2) -------
__global__ __launch_bounds__(256) void prep2(
    const float* __restrict__ W_ih, const float* __restrict__ W_hh,
    const float* __restrict__ b_ih, const float* __restrict__ b_hh,
    const float* __restrict__ W1, const float* __restrict__ W2,
    float* __restrict__ ws)
{
  int tid = blockIdx.x*blockDim.x + threadIdx.x;
  int stride = gridDim.x*blockDim.x;
  unsigned short* Ap  = (unsigned short*)((char*)ws + APACK_OFF);
  float*          B4  = (float*)((char*)ws + BIAS4_OFF);
  unsigned short* W1p = (unsigned short*)((char*)ws + W1P_OFF);
  unsigned short* W2p = (unsigned short*)((char*)ws + W2P_OFF);

  for (int s = tid; s < 19*12*64; s += stride){
    int lane = s & 63; int t2 = s >> 6; int ks = t2 % 12; int mt = t2 / 12;
    int R = mt*32 + (lane & 31);
    int kb = ks*16 + (lane >> 5)*8;
    int j = R >> 2, g = R & 3;
    #pragma unroll
    for (int i=0;i<8;i++){
      int k = kb + i; float f = 0.f;
      if (j < 150){
        if (k < 150){
          if (g==0) f = W_hh[j*150+k];
          else if (g==1) f = W_hh[(150+j)*150+k];
          else if (g==2) f = W_hh[(300+j)*150+k];
        } else if (k < 162){
          int kx = k - 150;
          if (g==0) f = W_ih[j*12+kx];
          else if (g==1) f = W_ih[(150+j)*12+kx];
          else if (g==3) f = W_ih[(300+j)*12+kx];
        }
      }
      Ap[s*8+i] = f2b(f);
    }
  }
  for (int j = tid; j < 152; j += stride){
    float4 bv = make_float4(0.f,0.f,0.f,0.f);
    if (j < 150){
      bv.x = b_ih[j]       + b_hh[j];
      bv.y = b_ih[150+j]   + b_hh[150+j];
      bv.z = b_hh[300+j];
      bv.w = b_ih[300+j];
    }
    ((float4*)B4)[j] = bv;
  }
  for (int s = tid; s < 2*13*64; s += stride){
    int lane = s & 63; int t2 = s >> 6; int ks = t2 % 13; int mt = t2 / 13;
    int o = mt*32 + (lane & 31);
    int kb = ks*16 + (lane >> 5)*8;
    #pragma unroll
    for (int i=0;i<8;i++){
      int k = kb + i;
      float f = (o < 50 && k < 200) ? W1[o*200+k] : 0.f;
      W1p[s*8+i] = f2b(f);
    }
  }
  for (int s = tid; s < 2*4*64; s += stride){
    int lane = s & 63; int t2 = s >> 6; int ks = t2 % 4; int mt = t2 / 4;
    int o = mt*32 + (lane & 31);
    int kb = ks*16 + (lane >> 5)*8;
    #pragma unroll
    for (int i=0;i<8;i++){
      int k = kb + i;
      float f = (o < 50 && k < 50) ? W2[o*50+k] : 0.f;
      W2p[s*8+i] = f2b(f);
    }
  }
}

// ---------------- fused GRU + MLP + head -------------------------------
// Per block: 64 agents. LDS row per agent: [h(150)|static(50)|pad] bf16,
// stride 216 bf16 = 432 B (27x16B -> conflict-free b128 frag reads).
__global__ __launch_bounds__(256,3) void fused_kernel(
    const float* __restrict__ x_flat, const float* __restrict__ h_in,
    const float* __restrict__ st, const float* __restrict__ z_in,
    const float* __restrict__ dx, const float* __restrict__ xp,
    const float* __restrict__ b1, const float* __restrict__ b2,
    const float* __restrict__ W3, const float* __restrict__ b3,
    const unsigned short* __restrict__ Apack, const float* __restrict__ Bias4,
    const unsigned short* __restrict__ W1p, const unsigned short* __restrict__ W2p,
    float* __restrict__ out)
{
  __shared__ unsigned short sm_ag[64*216];  // 27648 B
  __shared__ float          sm_x[64*13];    //  3328 B
  __shared__ unsigned short sm_h1[64*72];   //  9216 B
  __shared__ float          sm_h2[64*51];   // 13056 B

  int t = threadIdx.x; int lane = t & 63; int w = t >> 6;
  int hi = lane >> 5, cl = lane & 31;
  long ab = (long)blockIdx.x * 64;
  unsigned* ag32 = (unsigned*)sm_ag;

  // zero h1 (cols 50..71 stay zero as MLP2 K-pad)
  for (int s = t; s < 64*36; s += 256) ((unsigned*)sm_h1)[s] = 0u;
  // stage h (coalesced float2 -> packed bf16)
  const float2* h2p = (const float2*)h_in;
  for (int s = t; s < 4800; s += 256){
    int a = s/75, k2 = s - a*75;
    float2 v = h2p[ab*75 + s];
    ag32[a*108 + k2] = (unsigned)f2b(v.x) | ((unsigned)f2b(v.y) << 16);
  }
  // stage static
  const float2* s2p = (const float2*)st;
  for (int s = t; s < 1600; s += 256){
    int a = s/25, k2 = s - a*25;
    float2 v = s2p[ab*25 + s];
    ag32[a*108 + 75 + k2] = (unsigned)f2b(v.x) | ((unsigned)f2b(v.y) << 16);
  }
  // zero row pad (cols 200..215)
  for (int s = t; s < 512; s += 256)
    ag32[(s>>3)*108 + 100 + (s&7)] = 0u;
  // stage x (f32)
  for (int s = t; s < 768; s += 256){
    int a = s/12, k = s - a*12;
    sm_x[a*13 + k] = x_flat[ab*12 + s];
  }
  __syncthreads();

  // ---- GRU B-frags from LDS (per wave, registers) ----
  bf16x8 B0[11], B1[11];
  {
    const uint4* r0 = (const uint4*)(sm_ag + cl*216);
    const uint4* r1 = (const uint4*)(sm_ag + (32+cl)*216);
    #pragma unroll
    for (int ks=0; ks<9; ks++){
      B0[ks] = asb(r0[ks*2+hi]);
      B1[ks] = asb(r1[ks*2+hi]);
    }
    #pragma unroll
    for (int ks=9; ks<11; ks++){
      unsigned short v0[8], v1[8];
      #pragma unroll
      for (int i=0;i<8;i++){
        int k = ks*16 + hi*8 + i;
        unsigned short e0=0, e1=0;
        if (k < 150){ e0 = sm_ag[cl*216+k]; e1 = sm_ag[(32+cl)*216+k]; }
        else if (k < 162){
          e0 = f2b(sm_x[cl*13 + (k-150)]);
          e1 = f2b(sm_x[(32+cl)*13 + (k-150)]);
        }
        v0[i]=e0; v1[i]=e1;
      }
      B0[ks] = asb(packv(v0)); B1[ks] = asb(packv(v1));
    }
  }
  __syncthreads();   // all h0 frag reads complete before in-place h_new writes

  // ---- GRU MFMA + gate epilogue (h_new written in place, bf16) ----
  const uint4* ApV = (const uint4*)Apack;
  #pragma unroll 1
  for (int mt = w; mt < 19; mt += 4){
    f32x16 acc0;
    #pragma unroll
    for (int q=0;q<4;q++){
      float4 bq = ((const float4*)Bias4)[mt*8 + 2*q + hi];
      acc0[4*q+0]=bq.x; acc0[4*q+1]=bq.y; acc0[4*q+2]=bq.z; acc0[4*q+3]=bq.w;
    }
    f32x16 acc1 = acc0;
    const uint4* ap = ApV + (size_t)(mt*12)*64 + lane;
    #pragma unroll
    for (int ks=0; ks<11; ks++){
      bf16x8 af = asb(ap[ks*64]);
      acc0 = mfma32(af, B0[ks], acc0);
      acc1 = mfma32(af, B1[ks], acc1);
    }
    #pragma unroll
    for (int nt=0; nt<2; nt++){
      const f32x16& acc = nt ? acc1 : acc0;
      int a = nt*32 + cl;
      #pragma unroll
      for (int q=0;q<4;q++){
        int j = mt*8 + 2*q + hi;
        if (j < 150){
          float h0 = b2f(sm_ag[a*216 + j]);
          float r = fsigmoid(acc[4*q+0]);
          float z = fsigmoid(acc[4*q+1]);
          float n = ftanh(acc[4*q+3] + r*acc[4*q+2]);
          sm_ag[a*216 + j] = f2b(n + z*(h0 - n));
        }
      }
    }
  }
  __syncthreads();

  // ---- flush h_new coalesced ----
  float2* oh2 = (float2*)(out + (size_t)8*NA);
  for (int s = t; s < 4800; s += 256){
    int a = s/75, k2 = s - a*75;
    unsigned u = ag32[a*108 + k2];
    float2 v; v.x = b2f((unsigned short)u); v.y = b2f((unsigned short)(u>>16));
    oh2[ab*75 + s] = v;
  }

  // ---- MLP1: 200 -> 50, softplus ----
  int mt2 = w >> 1; int a2 = (w & 1)*32 + cl;
  f32x16 acc;
  #pragma unroll
  for (int r=0;r<16;r++){
    int o = mt2*32 + (r&3) + 8*(r>>2) + 4*hi;
    acc[r] = (o < 50) ? b1[o] : 0.f;
  }
  {
    const uint4* rv  = (const uint4*)(sm_ag + a2*216);
    const uint4* w1v = (const uint4*)W1p;
    #pragma unroll
    for (int ks=0; ks<13; ks++){
      acc = mfma32(asb(w1v[(mt2*13+ks)*64 + lane]), asb(rv[ks*2+hi]), acc);
    }
  }
  #pragma unroll
  for (int r=0;r<16;r++){
    int o = mt2*32 + (r&3) + 8*(r>>2) + 4*hi;
    if (o < 50){
      float xx = acc[r];
      float spv = fmaxf(xx,0.f) + __logf(1.f + __expf(-fabsf(xx)));
      sm_h1[a2*72 + o] = f2b(spv);
    }
  }
  __syncthreads();

  // ---- MLP2: 50 -> 50, tanh ----
  f32x16 acc2;
  #pragma unroll
  for (int r=0;r<16;r++){
    int o = mt2*32 + (r&3) + 8*(r>>2) + 4*hi;
    acc2[r] = (o < 50) ? b2[o] : 0.f;
  }
  {
    const uint4* r1v = (const uint4*)(sm_h1 + a2*72);
    const uint4* w2v = (const uint4*)W2p;
    #pragma unroll
    for (int ks=0; ks<4; ks++){
      acc2 = mfma32(asb(w2v[(mt2*4+ks)*64 + lane]), asb(r1v[ks*2+hi]), acc2);
    }
  }
  #pragma unroll
  for (int r=0;r<16;r++){
    int o = mt2*32 + (r&3) + 8*(r>>2) + 4*hi;
    if (o < 50) sm_h2[a2*51 + o] = ftanh(acc2[r]);
  }
  __syncthreads();

  // ---- head: 50 -> 6 + distribution math ----
  if (t < 64){
    int a = t; long ga = ab + a;
    float o6[6];
    #pragma unroll
    for (int jj=0;jj<6;jj++) o6[jj] = b3[jj];
    for (int k=0;k<50;k++){
      float v = sm_h2[a*51 + k];
      #pragma unroll
      for (int jj=0;jj<6;jj++) o6[jj] = fmaf(v, W3[jj*50+k], o6[jj]);
    }
    float mu0 = xp[ga*2+0] + 0.5f*dx[ga*2+0] + o6[0];
    float mu1 = xp[ga*2+1] + 0.5f*dx[ga*2+1] + o6[1];
    float bb  = o6[3] + o6[4];
    float apd = o6[2] + o6[5];
    float amd = o6[2] - o6[5];
    float delta = sqrtf(amd*amd + bb*bb);
    float e  = __expf(delta);
    float ei = 1.f/e;
    float sinh_ = 0.5f*(e - ei);
    float cosh_ = 0.5f*(e + ei);
    float tmp1 = sinh_/delta;
    float tmp2 = amd/tmp1;
    float ea = __expf(apd);
    float s00 = (cosh_+tmp2)*ea;
    float s01 = (bb*tmp1)*ea;
    float s11 = (cosh_-tmp2)*ea;
    float z0 = z_in[ga*2+0], z1 = z_in[ga*2+1];
    out[ga*2+0] = s00*z0 + s01*z1 + mu0;
    out[ga*2+1] = s01*z0 + s11*z1 + mu1;
    out[(size_t)2*NA + ga*2+0] = mu0;
    out[(size_t)2*NA + ga*2+1] = mu1;
    out[(size_t)4*NA + ga*4+0] = s00;
    out[(size_t)4*NA + ga*4+1] = s01;
    out[(size_t)4*NA + ga*4+2] = s01;
    out[(size_t)4*NA + ga*4+3] = s11;
  }
}

extern "C" void kernel_launch(void* const* d_in, const int* in_sizes, int n_in,
                              void* d_out, int out_size, void* d_ws, size_t ws_size,
                              hipStream_t stream) {
  const float* z      = (const float*)d_in[0];
  const float* x_flat = (const float*)d_in[1];
  const float* h      = (const float*)d_in[2];
  const float* st     = (const float*)d_in[3];
  const float* dx     = (const float*)d_in[4];
  const float* xp     = (const float*)d_in[5];
  const float* W_ih   = (const float*)d_in[6];
  const float* W_hh   = (const float*)d_in[7];
  const float* b_ih   = (const float*)d_in[8];
  const float* b_hh   = (const float*)d_in[9];
  const float* W1     = (const float*)d_in[10];
  const float* b1     = (const float*)d_in[11];
  const float* W2     = (const float*)d_in[12];
  const float* b2     = (const float*)d_in[13];
  const float* W3     = (const float*)d_in[14];
  const float* b3     = (const float*)d_in[15];
  float* out = (float*)d_out;
  float* ws  = (float*)d_ws;

  const unsigned short* Apack = (const unsigned short*)((char*)ws + APACK_OFF);
  const float*          Bias4 = (const float*)((char*)ws + BIAS4_OFF);
  const unsigned short* W1p   = (const unsigned short*)((char*)ws + W1P_OFF);
  const unsigned short* W2p   = (const unsigned short*)((char*)ws + W2P_OFF);

  hipLaunchKernelGGL(prep2, dim3(128), dim3(256), 0, stream,
                     W_ih, W_hh, b_ih, b_hh, W1, W2, ws);
  hipLaunchKernelGGL(fused_kernel, dim3(NBLK), dim3(256), 0, stream,
                     x_flat, h, st, z, dx, xp, b1, b2, W3, b3,
                     Apack, Bias4, W1p, W2p, out);
}